// Round 1
// baseline (452.963 us; speedup 1.0000x reference)
//
#include <hip/hip_runtime.h>
#include <hip/hip_bf16.h>
#include <stdint.h>

#define BM 128
#define BN 128
#define BK 32

typedef __bf16 bf16;
typedef bf16 bf16x8 __attribute__((ext_vector_type(8)));
typedef float f32x4 __attribute__((ext_vector_type(4)));

typedef const __attribute__((address_space(1))) void* gas1_t;
typedef __attribute__((address_space(3))) void* las3_t;

__device__ __forceinline__ void gl_lds16(const void* g, void* l) {
  __builtin_amdgcn_global_load_lds((gas1_t)g, (las3_t)l, 16, 0, 0);
}

// ---------------- shared GEMM core ----------------
// C(128x128) = A_tile * Bt_tile^T, bf16 inputs, f32 accum.
// A:  row-major [.][lda], tile starts at A   (rows m0..m0+127, k contiguous)
// Bt: row-major [.][ldb], tile starts at Bt  (rows n0..n0+127, k contiguous)
__device__ __forceinline__ void gemm_core(const bf16* A, const bf16* Bt,
                                          int lda, int ldb, int kTiles,
                                          bf16* As, bf16* Bs, f32x4 acc[4][4]) {
  const int tid = threadIdx.x;       // 0..255
  const int lane = tid & 63;
  const int wid = tid >> 6;          // 0..3
  const int wr = wid >> 1, wc = wid & 1;
  const int lr = lane & 15, lg = lane >> 4;

  for (int kt = 0; kt < kTiles; ++kt) {
    const bf16* Ak = A + kt * BK;
    const bf16* Bk = Bt + kt * BK;
#pragma unroll
    for (int p = 0; p < 2; ++p) {
      int c = p * 256 + tid;               // 16B chunk index, 512 chunks = 8KB
      int row = c >> 2, k8 = (c & 3) << 3; // [128 rows][32 k]
      gl_lds16(Ak + (size_t)row * lda + k8, As + c * 8);
      gl_lds16(Bk + (size_t)row * ldb + k8, Bs + c * 8);
    }
    __syncthreads();
    bf16x8 af[4], bfr[4];
#pragma unroll
    for (int i = 0; i < 4; ++i) {
      af[i]  = *(const bf16x8*)(As + (wr * 64 + i * 16 + lr) * BK + lg * 8);
      bfr[i] = *(const bf16x8*)(Bs + (wc * 64 + i * 16 + lr) * BK + lg * 8);
    }
#pragma unroll
    for (int i = 0; i < 4; ++i)
#pragma unroll
      for (int j = 0; j < 4; ++j)
        acc[i][j] = __builtin_amdgcn_mfma_f32_16x16x32_bf16(af[i], bfr[j], acc[i][j], 0, 0, 0);
    __syncthreads();
  }
}

// ---------------- small prep kernels ----------------
__global__ __launch_bounds__(256) void k_cast(const float* __restrict__ in,
                                              bf16* __restrict__ out, int n8) {
  int i = blockIdx.x * blockDim.x + threadIdx.x;
  int stride = gridDim.x * blockDim.x;
  for (; i < n8; i += stride) {
    float4 a = ((const float4*)in)[2 * (size_t)i];
    float4 b = ((const float4*)in)[2 * (size_t)i + 1];
    bf16x8 o;
    o[0] = (bf16)a.x; o[1] = (bf16)a.y; o[2] = (bf16)a.z; o[3] = (bf16)a.w;
    o[4] = (bf16)b.x; o[5] = (bf16)b.y; o[6] = (bf16)b.z; o[7] = (bf16)b.w;
    ((bf16x8*)out)[i] = o;
  }
}

// Wt[n][k] = (n<512 ? Wk[k][n] : Wv[k][n-512]), bf16, [1024][1024]
__global__ __launch_bounds__(256) void k_buildwt(const float* __restrict__ Wk,
                                                 const float* __restrict__ Wv,
                                                 bf16* __restrict__ Wt) {
  int n = blockIdx.x;                 // 0..1023
  const float* W = (n < 512) ? Wk : Wv;
  int col = n & 511;
  for (int k = threadIdx.x; k < 1024; k += 256)
    Wt[(size_t)n * 1024 + k] = (bf16)W[(size_t)k * 512 + col];
}

// ---------------- projection: [16384x1024] x Wt^T -> K (row-major) + V^T ----------------
__global__ __launch_bounds__(256) void k_proj(const bf16* __restrict__ S,
                                              const bf16* __restrict__ Wt,
                                              const float* __restrict__ bk,
                                              const float* __restrict__ bv,
                                              bf16* __restrict__ Kb,
                                              bf16* __restrict__ VT) {
  __shared__ bf16 As[BM * BK], Bs[BN * BK];
  f32x4 acc[4][4] = {};
  int m0 = blockIdx.x * BM, n0 = blockIdx.y * BN;
  gemm_core(S + (size_t)m0 * 1024, Wt + (size_t)n0 * 1024, 1024, 1024, 1024 / BK, As, Bs, acc);
  const int lane = threadIdx.x & 63, wid = threadIdx.x >> 6;
  const int wr = wid >> 1, wc = wid & 1, lr = lane & 15, lg = lane >> 4;
#pragma unroll
  for (int i = 0; i < 4; ++i) {
    int gmb = m0 + wr * 64 + i * 16 + lg * 4;
#pragma unroll
    for (int j = 0; j < 4; ++j) {
      int gn = n0 + wc * 64 + j * 16 + lr;
      f32x4 v = acc[i][j];
      if (gn < 512) {
        float bias = bk[gn];
#pragma unroll
        for (int r = 0; r < 4; ++r)
          Kb[(size_t)(gmb + r) * 512 + gn] = (bf16)(v[r] + bias);
      } else {
        float bias = bv[gn - 512];
#pragma unroll
        for (int r = 0; r < 4; ++r) {
          int gm = gmb + r, b = gm >> 11, s = gm & 2047;
          VT[((size_t)(b * 512 + (gn - 512))) * 2048 + s] = (bf16)(v[r] + bias);
        }
      }
    }
  }
}

// ---------------- scores: P = exp(scale * (Q K^T) * mask), l += rowsum ----------------
__global__ __launch_bounds__(256) void k_scores(const bf16* __restrict__ Qb,
                                                const bf16* __restrict__ Kb,
                                                const float* __restrict__ mask,
                                                bf16* __restrict__ P,
                                                float* __restrict__ lsum) {
  __shared__ bf16 As[BM * BK], Bs[BN * BK];
  f32x4 acc[4][4] = {};
  int b = blockIdx.z;
  int m0 = blockIdx.x * BM, n0 = blockIdx.y * BN;
  gemm_core(Qb + (size_t)b * 2048 * 512 + (size_t)m0 * 512,
            Kb + (size_t)b * 2048 * 512 + (size_t)n0 * 512, 512, 512, 512 / BK, As, Bs, acc);
  const float scale = 0.04419417382415922f;  // 1/sqrt(512)
  const float* Mb = mask + (size_t)b * 2048 * 2048;
  bf16* Pb = P + (size_t)b * 2048 * 2048;
  const int lane = threadIdx.x & 63, wid = threadIdx.x >> 6;
  const int wr = wid >> 1, wc = wid & 1, lr = lane & 15, lg = lane >> 4;
  float rs[4][4];
#pragma unroll
  for (int i = 0; i < 4; ++i)
#pragma unroll
    for (int r = 0; r < 4; ++r) rs[i][r] = 0.f;
#pragma unroll
  for (int i = 0; i < 4; ++i) {
    int gmb = m0 + wr * 64 + i * 16 + lg * 4;
#pragma unroll
    for (int j = 0; j < 4; ++j) {
      int gn = n0 + wc * 64 + j * 16 + lr;
      f32x4 v = acc[i][j];
#pragma unroll
      for (int r = 0; r < 4; ++r) {
        size_t off = (size_t)(gmb + r) * 2048 + gn;
        float p = __expf(v[r] * scale * Mb[off]);  // no max-sub needed: |s| <~ 6
        Pb[off] = (bf16)p;
        rs[i][r] += p;
      }
    }
  }
#pragma unroll
  for (int i = 0; i < 4; ++i)
#pragma unroll
    for (int r = 0; r < 4; ++r) {
      float v = rs[i][r];
      v += __shfl_xor(v, 1, 16);
      v += __shfl_xor(v, 2, 16);
      v += __shfl_xor(v, 4, 16);
      v += __shfl_xor(v, 8, 16);
      if (lr == 0)
        atomicAdd(&lsum[b * 2048 + m0 + wr * 64 + i * 16 + lg * 4 + r], v);
    }
}

// ---------------- PV: out = (P V) / l ----------------
__global__ __launch_bounds__(256) void k_pv(const bf16* __restrict__ P,
                                            const bf16* __restrict__ VT,
                                            const float* __restrict__ lsum,
                                            float* __restrict__ out) {
  __shared__ bf16 As[BM * BK], Bs[BN * BK];
  f32x4 acc[4][4] = {};
  int b = blockIdx.z;
  int m0 = blockIdx.x * BM, n0 = blockIdx.y * BN;
  gemm_core(P + (size_t)b * 2048 * 2048 + (size_t)m0 * 2048,
            VT + (size_t)b * 512 * 2048 + (size_t)n0 * 2048, 2048, 2048, 2048 / BK, As, Bs, acc);
  float* Ob = out + (size_t)b * 2048 * 512;
  const float* lb = lsum + b * 2048;
  const int lane = threadIdx.x & 63, wid = threadIdx.x >> 6;
  const int wr = wid >> 1, wc = wid & 1, lr = lane & 15, lg = lane >> 4;
#pragma unroll
  for (int i = 0; i < 4; ++i) {
    int gmb = m0 + wr * 64 + i * 16 + lg * 4;
#pragma unroll
    for (int j = 0; j < 4; ++j) {
      int gn = n0 + wc * 64 + j * 16 + lr;
      f32x4 v = acc[i][j];
#pragma unroll
      for (int r = 0; r < 4; ++r)
        Ob[(size_t)(gmb + r) * 512 + gn] = v[r] / lb[gmb + r];
    }
  }
}

// ---------------- launcher ----------------
extern "C" void kernel_launch(void* const* d_in, const int* in_sizes, int n_in,
                              void* d_out, int out_size, void* d_ws, size_t ws_size,
                              hipStream_t stream) {
  const float* query  = (const float*)d_in[0];
  const float* states = (const float*)d_in[1];
  const float* mask   = (const float*)d_in[2];
  const float* Wk     = (const float*)d_in[3];
  const float* bk     = (const float*)d_in[4];
  const float* Wv     = (const float*)d_in[5];
  const float* bv     = (const float*)d_in[6];
  float* out = (float*)d_out;

  char* ws = (char*)d_ws;
  bf16* WT = (bf16*)(ws);                    //  2 MB  [1024][1024] (K|V)^T
  bf16* Qb = (bf16*)(ws + (2ull << 20));     // 16 MB  [8][2048][512]
  bf16* Kb = (bf16*)(ws + (18ull << 20));    // 16 MB  [8][2048][512]
  bf16* VT = (bf16*)(ws + (34ull << 20));    // 16 MB  [8][512][2048]
  bf16* Sb = (bf16*)(ws + (50ull << 20));    // 32 MB  [16384][1024] (dead after proj)
  bf16* P  = (bf16*)(ws + (50ull << 20));    // 64 MB  [8][2048][2048] overlays Sb
  float* ls = (float*)(ws + (114ull << 20)); // 64 KB  [8][2048]

  hipMemsetAsync(ls, 0, 8 * 2048 * sizeof(float), stream);
  k_buildwt<<<dim3(1024), 256, 0, stream>>>(Wk, Wv, WT);
  k_cast<<<dim3(2048), 256, 0, stream>>>(states, Sb, 16384 * 1024 / 8);
  k_cast<<<dim3(1024), 256, 0, stream>>>(query, Qb, 8 * 2048 * 512 / 8);
  k_proj<<<dim3(128, 8), 256, 0, stream>>>(Sb, WT, bk, bv, Kb, VT);
  k_scores<<<dim3(16, 16, 8), 256, 0, stream>>>(Qb, Kb, mask, P, ls);
  k_pv<<<dim3(16, 4, 8), 256, 0, stream>>>(P, VT, ls, out);
}

// Round 3
// 450.051 us; speedup vs baseline: 1.0065x; 1.0065x over previous
//
#include <hip/hip_runtime.h>
#include <hip/hip_bf16.h>
#include <stdint.h>

#define BM 128
#define BN 128
#define BK 32

typedef __bf16 bf16;
typedef bf16 bf16x4 __attribute__((ext_vector_type(4)));
typedef bf16 bf16x8 __attribute__((ext_vector_type(8)));
typedef float f32x4 __attribute__((ext_vector_type(4)));

typedef const __attribute__((address_space(1))) void* gas1_t;
typedef __attribute__((address_space(3))) void* las3_t;

__device__ __forceinline__ void gl_lds16(const void* g, void* l) {
  __builtin_amdgcn_global_load_lds((gas1_t)g, (las3_t)l, 16, 0, 0);
}

// ---------------- shared GEMM core ----------------
// acc[i][j] = Arows(m) x Brows(n)^T tile product, bf16 in, f32 accum.
// Lane->element: m = m0 + wr*64 + i*16 + (lane>>4)*4 + r ; n = n0 + wc*64 + j*16 + (lane&15)
__device__ __forceinline__ void gemm_core(const bf16* A, const bf16* Bt,
                                          int lda, int ldb, int kTiles,
                                          bf16* As, bf16* Bs, f32x4 acc[4][4]) {
  const int tid = threadIdx.x;       // 0..255
  const int lane = tid & 63;
  const int wid = tid >> 6;          // 0..3
  const int wr = wid >> 1, wc = wid & 1;
  const int lr = lane & 15, lg = lane >> 4;

  for (int kt = 0; kt < kTiles; ++kt) {
    const bf16* Ak = A + kt * BK;
    const bf16* Bk = Bt + kt * BK;
#pragma unroll
    for (int p = 0; p < 2; ++p) {
      int c = p * 256 + tid;               // 16B chunk index, 512 chunks = 8KB
      int row = c >> 2, k8 = (c & 3) << 3; // [128 rows][32 k]
      gl_lds16(Ak + (size_t)row * lda + k8, As + c * 8);
      gl_lds16(Bk + (size_t)row * ldb + k8, Bs + c * 8);
    }
    __syncthreads();
    bf16x8 af[4], bfr[4];
#pragma unroll
    for (int i = 0; i < 4; ++i) {
      af[i]  = *(const bf16x8*)(As + (wr * 64 + i * 16 + lr) * BK + lg * 8);
      bfr[i] = *(const bf16x8*)(Bs + (wc * 64 + i * 16 + lr) * BK + lg * 8);
    }
#pragma unroll
    for (int i = 0; i < 4; ++i)
#pragma unroll
      for (int j = 0; j < 4; ++j)
        acc[i][j] = __builtin_amdgcn_mfma_f32_16x16x32_bf16(af[i], bfr[j], acc[i][j], 0, 0, 0);
    __syncthreads();
  }
}

// ---------------- prep kernels ----------------
__global__ __launch_bounds__(256) void k_cast(const float* __restrict__ in,
                                              bf16* __restrict__ out, int n8) {
  int i = blockIdx.x * blockDim.x + threadIdx.x;
  int stride = gridDim.x * blockDim.x;
  for (; i < n8; i += stride) {
    float4 a = ((const float4*)in)[2 * (size_t)i];
    float4 b = ((const float4*)in)[2 * (size_t)i + 1];
    bf16x8 o;
    o[0] = (bf16)a.x; o[1] = (bf16)a.y; o[2] = (bf16)a.z; o[3] = (bf16)a.w;
    o[4] = (bf16)b.x; o[5] = (bf16)b.y; o[6] = (bf16)b.z; o[7] = (bf16)b.w;
    ((bf16x8*)out)[i] = o;
  }
}

// Transpose W [1024 din][512 h] f32 -> WT [512 h][1024 din] bf16 (z: 0=Wk,1=Wv)
__global__ __launch_bounds__(256) void k_transposeW(const float* __restrict__ Wk,
                                                    const float* __restrict__ Wv,
                                                    bf16* __restrict__ WT) {
  __shared__ float t[32][33];
  const float* W = blockIdx.z ? Wv : Wk;
  bf16* O = WT + (size_t)blockIdx.z * 512 * 1024;
  int h0 = blockIdx.x * 32, d0 = blockIdx.y * 32;
  int tx = threadIdx.x & 31, ty = threadIdx.x >> 5;  // 32 x 8
#pragma unroll
  for (int yy = 0; yy < 4; ++yy)
    t[ty + yy * 8][tx] = W[(size_t)(d0 + ty + yy * 8) * 512 + h0 + tx];
  __syncthreads();
#pragma unroll
  for (int yy = 0; yy < 4; ++yy)
    O[(size_t)(h0 + ty + yy * 8) * 1024 + d0 + tx] = (bf16)t[tx][ty + yy * 8];
}

// ---------------- K projection (swapped): acc m-side = h, n-side = token ----------------
// Kb[t][h] = sum_d WkT[h][d]*S[t][d] + bk[h]
__global__ __launch_bounds__(256) void k_projK(const bf16* __restrict__ WkT,
                                               const bf16* __restrict__ S,
                                               const float* __restrict__ bk,
                                               bf16* __restrict__ Kb) {
  __shared__ bf16 As[BM * BK], Bs[BN * BK];
  f32x4 acc[4][4] = {};
  int h0 = blockIdx.x * BM, t0 = blockIdx.y * BN;
  gemm_core(WkT + (size_t)h0 * 1024, S + (size_t)t0 * 1024, 1024, 1024, 1024 / BK, As, Bs, acc);
  const int lane = threadIdx.x & 63, wid = threadIdx.x >> 6;
  const int wr = wid >> 1, wc = wid & 1, lr = lane & 15, lg = lane >> 4;
#pragma unroll
  for (int i = 0; i < 4; ++i) {
    int hb = h0 + wr * 64 + i * 16 + lg * 4;
    float4 bias = *(const float4*)(bk + hb);
#pragma unroll
    for (int j = 0; j < 4; ++j) {
      int t = t0 + wc * 64 + j * 16 + lr;
      f32x4 v = acc[i][j];
      bf16x4 o;
      o[0] = (bf16)(v[0] + bias.x); o[1] = (bf16)(v[1] + bias.y);
      o[2] = (bf16)(v[2] + bias.z); o[3] = (bf16)(v[3] + bias.w);
      *(bf16x4*)(Kb + (size_t)t * 512 + hb) = o;
    }
  }
}

// ---------------- V projection (unswapped): acc m-side = token, n-side = h ----------------
// VT[b][h][s] = sum_d S[t][d]*WvT[h][d] + bv[h],  t = b*2048+s
__global__ __launch_bounds__(256) void k_projV(const bf16* __restrict__ S,
                                               const bf16* __restrict__ WvT,
                                               const float* __restrict__ bv,
                                               bf16* __restrict__ VT) {
  __shared__ bf16 As[BM * BK], Bs[BN * BK];
  f32x4 acc[4][4] = {};
  int t0 = blockIdx.x * BM, h0 = blockIdx.y * BN;
  gemm_core(S + (size_t)t0 * 1024, WvT + (size_t)h0 * 1024, 1024, 1024, 1024 / BK, As, Bs, acc);
  const int lane = threadIdx.x & 63, wid = threadIdx.x >> 6;
  const int wr = wid >> 1, wc = wid & 1, lr = lane & 15, lg = lane >> 4;
#pragma unroll
  for (int i = 0; i < 4; ++i) {
    int tb = t0 + wr * 64 + i * 16 + lg * 4;
    int b = tb >> 11, s = tb & 2047;
#pragma unroll
    for (int j = 0; j < 4; ++j) {
      int h = h0 + wc * 64 + j * 16 + lr;
      float bias = bv[h];
      f32x4 v = acc[i][j];
      bf16x4 o;
      o[0] = (bf16)(v[0] + bias); o[1] = (bf16)(v[1] + bias);
      o[2] = (bf16)(v[2] + bias); o[3] = (bf16)(v[3] + bias);
      *(bf16x4*)(VT + ((size_t)(b * 512 + h)) * 2048 + s) = o;
    }
  }
}

// ---------------- scores (swapped): acc m-side = kv, n-side = q ----------------
// P[q][kv] = exp(scale * (Q[q].K[kv]) * mask[q][kv]);  lsum[q] += rowsum
__global__ __launch_bounds__(256) void k_scores(const bf16* __restrict__ Kb,
                                                const bf16* __restrict__ Qb,
                                                const float* __restrict__ mask,
                                                bf16* __restrict__ P,
                                                float* __restrict__ lsum) {
  __shared__ bf16 As[BM * BK], Bs[BN * BK];
  f32x4 acc[4][4] = {};
  int b = blockIdx.z;
  int kv0 = blockIdx.x * BM, q0 = blockIdx.y * BN;
  gemm_core(Kb + (size_t)b * 2048 * 512 + (size_t)kv0 * 512,
            Qb + (size_t)b * 2048 * 512 + (size_t)q0 * 512, 512, 512, 512 / BK, As, Bs, acc);
  const float scale = 0.04419417382415922f;  // 1/sqrt(512)
  const float* Mb = mask + (size_t)b * 2048 * 2048;
  bf16* Pb = P + (size_t)b * 2048 * 2048;
  const int lane = threadIdx.x & 63, wid = threadIdx.x >> 6;
  const int wr = wid >> 1, wc = wid & 1, lr = lane & 15, lg = lane >> 4;
  float rs[4] = {0.f, 0.f, 0.f, 0.f};
#pragma unroll
  for (int j = 0; j < 4; ++j) {
    int q = q0 + wc * 64 + j * 16 + lr;
    size_t qrow = (size_t)q * 2048;
#pragma unroll
    for (int i = 0; i < 4; ++i) {
      int kvb = kv0 + wr * 64 + i * 16 + lg * 4;
      float4 m4 = *(const float4*)(Mb + qrow + kvb);
      f32x4 v = acc[i][j];
      float p0 = __expf(v[0] * scale * m4.x);
      float p1 = __expf(v[1] * scale * m4.y);
      float p2 = __expf(v[2] * scale * m4.z);
      float p3 = __expf(v[3] * scale * m4.w);
      bf16x4 o; o[0] = (bf16)p0; o[1] = (bf16)p1; o[2] = (bf16)p2; o[3] = (bf16)p3;
      *(bf16x4*)(Pb + qrow + kvb) = o;
      rs[j] += p0 + p1 + p2 + p3;
    }
  }
#pragma unroll
  for (int j = 0; j < 4; ++j) {
    float v = rs[j];
    v += __shfl_xor(v, 16);
    v += __shfl_xor(v, 32);
    if (lane < 16)
      atomicAdd(&lsum[b * 2048 + q0 + wc * 64 + j * 16 + lr], v);
  }
}

// ---------------- PV (swapped): acc m-side = h, n-side = q ----------------
// out[q][h] = (sum_kv VT[h][kv]*P[q][kv]) / l[q]
__global__ __launch_bounds__(256) void k_pv(const bf16* __restrict__ VT,
                                            const bf16* __restrict__ P,
                                            const float* __restrict__ lsum,
                                            float* __restrict__ out) {
  __shared__ bf16 As[BM * BK], Bs[BN * BK];
  f32x4 acc[4][4] = {};
  int b = blockIdx.z;
  int h0 = blockIdx.x * BM, q0 = blockIdx.y * BN;
  gemm_core(VT + (size_t)b * 512 * 2048 + (size_t)h0 * 2048,
            P + (size_t)b * 2048 * 2048 + (size_t)q0 * 2048, 2048, 2048, 2048 / BK, As, Bs, acc);
  float* Ob = out + (size_t)b * 2048 * 512;
  const float* lb = lsum + b * 2048;
  const int lane = threadIdx.x & 63, wid = threadIdx.x >> 6;
  const int wr = wid >> 1, wc = wid & 1, lr = lane & 15, lg = lane >> 4;
#pragma unroll
  for (int j = 0; j < 4; ++j) {
    int q = q0 + wc * 64 + j * 16 + lr;
    float inv = 1.0f / lb[q];
#pragma unroll
    for (int i = 0; i < 4; ++i) {
      int hb = h0 + wr * 64 + i * 16 + lg * 4;
      f32x4 v = acc[i][j];
      float4 o4 = make_float4(v[0] * inv, v[1] * inv, v[2] * inv, v[3] * inv);
      *(float4*)(Ob + (size_t)q * 512 + hb) = o4;
    }
  }
}

// ---------------- launcher ----------------
extern "C" void kernel_launch(void* const* d_in, const int* in_sizes, int n_in,
                              void* d_out, int out_size, void* d_ws, size_t ws_size,
                              hipStream_t stream) {
  const float* query  = (const float*)d_in[0];
  const float* states = (const float*)d_in[1];
  const float* mask   = (const float*)d_in[2];
  const float* Wk     = (const float*)d_in[3];
  const float* bk     = (const float*)d_in[4];
  const float* Wv     = (const float*)d_in[5];
  const float* bv     = (const float*)d_in[6];
  float* out = (float*)d_out;

  char* ws = (char*)d_ws;
  bf16* WT = (bf16*)(ws);                    //  2 MB  WkT[512][1024] | WvT[512][1024]
  bf16* Qb = (bf16*)(ws + (2ull << 20));     // 16 MB  [8][2048][512]
  bf16* Kb = (bf16*)(ws + (18ull << 20));    // 16 MB  [8][2048][512]
  bf16* VT = (bf16*)(ws + (34ull << 20));    // 16 MB  [8][512][2048]
  bf16* Sb = (bf16*)(ws + (50ull << 20));    // 32 MB  [16384][1024] (dead after proj)
  bf16* P  = (bf16*)(ws + (50ull << 20));    // 64 MB  [8][2048][2048] overlays Sb
  float* ls = (float*)(ws + (114ull << 20)); // 64 KB  [8][2048]

  bf16* WkT = WT;
  bf16* WvT = WT + (size_t)512 * 1024;

  hipMemsetAsync(ls, 0, 8 * 2048 * sizeof(float), stream);
  k_transposeW<<<dim3(16, 32, 2), 256, 0, stream>>>(Wk, Wv, WT);
  k_cast<<<dim3(2048), 256, 0, stream>>>(states, Sb, 16384 * 1024 / 8);
  k_cast<<<dim3(1024), 256, 0, stream>>>(query, Qb, 8 * 2048 * 512 / 8);
  k_projK<<<dim3(4, 128), 256, 0, stream>>>(WkT, Sb, bk, Kb);
  k_projV<<<dim3(128, 4), 256, 0, stream>>>(Sb, WvT, bv, VT);
  k_scores<<<dim3(16, 16, 8), 256, 0, stream>>>(Kb, Qb, mask, P, ls);
  k_pv<<<dim3(4, 16, 8), 256, 0, stream>>>(VT, P, ls, out);
}